// Round 9
// baseline (448.156 us; speedup 1.0000x reference)
//
#include <hip/hip_runtime.h>
#include <hip/hip_bf16.h>

typedef unsigned short u16;
typedef __attribute__((ext_vector_type(4))) unsigned short u16x4;
typedef __attribute__((ext_vector_type(8))) unsigned short u16x8;
typedef __attribute__((ext_vector_type(8))) short s16x8;
typedef __attribute__((ext_vector_type(4))) float f32x4;

__device__ __forceinline__ float bf2f(u16 u){
  union { unsigned int i; float f; } v; v.i = ((unsigned int)u) << 16; return v.f;
}
__device__ __forceinline__ u16 f2bf(float f){
  union { float f; unsigned int i; } v; v.f = f;
  unsigned int r = v.i + 0x7fffu + ((v.i >> 16) & 1u);   // round-nearest-even
  return (u16)(r >> 16);
}
// compiler-lowered RNE convert (gfx950: v_cvt_pk_bf16_f32)
__device__ __forceinline__ u16 f2bfh(float f){
  __hip_bfloat16 h = __float2bfloat16(f);
  return *reinterpret_cast<u16*>(&h);
}

// ---------------------------------------------------------------------------
// Weight prep: fp32 [COUT][CIN][5] -> fragment-major bf16
//   Wp[wv][kt][lane][8],  wv=o/16, lane=quad*16+lr,
//   element (wv,kt,lane,i) = W[o=wv*16+(lane&15)][k=kt*32+(lane>>4)*8+i],
//   k = s*CIN + c.  A wave's fragment load = 1 KB contiguous.
// ---------------------------------------------------------------------------
__global__ __launch_bounds__(256) void prep_w(
    const float* __restrict__ src, u16* __restrict__ dst, int cout, int cin)
{
  const int n  = cout * cin * 5;
  const int KT = (cin * 5) / 32;
  const int i = blockIdx.x * 256 + threadIdx.x;
  if (i >= n) return;
  const int ii   = i & 7;
  const int lane = (i >> 3) & 63;
  const int kt   = (i >> 9) % KT;
  const int wv   = i / (KT * 512);
  const int o = wv * 16 + (lane & 15);
  const int k = kt * 32 + (lane >> 4) * 8 + ii;
  const int s = k / cin;
  const int c = k - s * cin;
  dst[i] = f2bf(src[(o * cin + c) * 5 + s]);
}

// ---------------------------------------------------------------------------
// K0: transpose fe [B,64,E] (fp32) -> feT [B,E,64] (bf16)
// ---------------------------------------------------------------------------
__global__ __launch_bounds__(256) void transpose64(
    const float* __restrict__ x, u16* __restrict__ xT, int E)
{
  __shared__ u16 tile[64][66];
  const int b   = blockIdx.z;
  const int e0  = blockIdx.x * 64;
  const int col = threadIdx.x & 63;
  const int r   = threadIdx.x >> 6;
  const int e   = e0 + col;
  #pragma unroll
  for (int k = 0; k < 16; k++) {
    const int c = r * 16 + k;
    float v = 0.f;
    if (e < E) v = x[((size_t)b * 64 + c) * (size_t)E + e];
    tile[c][col] = f2bf(v);
  }
  __syncthreads();
  const int e_l  = threadIdx.x >> 2;
  const int part = threadIdx.x & 3;
  const int eg   = e0 + e_l;
  if (eg < E) {
    u16* dst = xT + ((size_t)b * E + eg) * 64 + part * 16;
    #pragma unroll
    for (int h = 0; h < 2; h++) {
      u16x8 v;
      #pragma unroll
      for (int cc = 0; cc < 8; cc++) v[cc] = tile[part * 16 + h * 8 + cc][e_l];
      *(u16x8*)(dst + h * 8) = v;
    }
  }
}

// ---------------------------------------------------------------------------
// conv1: y1b[b,e,o] = bf16( sum_k W[o,k]*F[k,e] + bias[o] )  (pre-norm,
// EDGE-major bf16). Swapped MFMA: D[row=edge][col=channel].
// 4-tile software pipeline: tile t+1's gidx+gathers fly under tile t's
// staging+MFMA+epilogue. Fragment-major W. LDS un-padded + XOR swizzle.
// ---------------------------------------------------------------------------
__global__ __launch_bounds__(512, 6) void conv1_mfma(
    const u16* __restrict__ xT, const int* __restrict__ gidx,
    const u16* __restrict__ Wp, const float* __restrict__ bias,
    u16* __restrict__ y1b, float2* __restrict__ partials, int E, int nbx)
{
  constexpr int CIN = 64, EPB = 64, SUB = 8, KT = 10, NTL = 4;
  constexpr int NT  = EPB / 16;                // 4
  __shared__ __align__(16) u16 F[5 * EPB * CIN];   // 40960 B, swizzled chunks

  const int b  = blockIdx.z;
  const int t  = threadIdx.x;
  const int e_l = t / SUB;                     // 0..63
  const int sub = t % SUB;                     // 0..7 (16B chunk id)
  const int lane = t & 63, wv = t >> 6;
  const int lr = lane & 15, quad = lane >> 4;
  const int tbeg = blockIdx.x * NTL;

  const u16* base  = xT + (size_t)b * E * CIN + sub * 8;
  const u16* wbase = Wp + ((size_t)wv * KT * 64 + lane) * 8;
  const int ch = wv * 16 + lr;
  const float bv = bias[ch];
  const int pc = (sub ^ (e_l & 7)) * 8;        // swizzled chunk offset

  // prologue: gidx + gathers for tile tbeg
  u16x8 raw[5];
  {
    int er = tbeg * EPB + e_l;
    const int e = er < E ? er : E - 1;
    const int4 g = *(const int4*)(gidx + ((size_t)b * E + e) * 4);
    int rows[5] = {e, g.x, g.y, g.z, g.w};
    #pragma unroll
    for (int j = 0; j < 5; j++)
      raw[j] = *(const u16x8*)(base + (size_t)rows[j] * CIN);
  }
  __builtin_amdgcn_sched_barrier(0);

  for (int it = 0; it < NTL; ++it) {
    const int tcur = tbeg + it;
    const bool hasNext = (it + 1 < NTL);

    // prefetch next tile's neighbor indices (latency hidden under staging)
    int4 gn; int en = 0;
    if (hasNext) {
      int er = (tcur + 1) * EPB + e_l;
      en = er < E ? er : E - 1;
      gn = *(const int4*)(gidx + ((size_t)b * E + en) * 4);
    }

    // stage F from raw (compiler waits raw here)
    {
      u16x8 o1, o2, o3, o4;
      #pragma unroll
      for (int c = 0; c < 8; c++) {
        const float a1 = bf2f(raw[1][c]), a2 = bf2f(raw[2][c]);
        const float a3 = bf2f(raw[3][c]), a4 = bf2f(raw[4][c]);
        o1[c] = f2bfh(a1 + a3);
        o2[c] = f2bfh(a2 + a4);
        o3[c] = f2bfh(fabsf(a1 - a3));
        o4[c] = f2bfh(fabsf(a2 - a4));
      }
      *(u16x8*)&F[(0 * EPB + e_l) * CIN + pc] = raw[0];
      *(u16x8*)&F[(1 * EPB + e_l) * CIN + pc] = o1;
      *(u16x8*)&F[(2 * EPB + e_l) * CIN + pc] = o2;
      *(u16x8*)&F[(3 * EPB + e_l) * CIN + pc] = o3;
      *(u16x8*)&F[(4 * EPB + e_l) * CIN + pc] = o4;
    }
    __syncthreads();

    // issue next tile's gathers: fly under MFMA + epilogue + barrier
    if (hasNext) {
      int rows[5] = {en, gn.x, gn.y, gn.z, gn.w};
      #pragma unroll
      for (int j = 0; j < 5; j++)
        raw[j] = *(const u16x8*)(base + (size_t)rows[j] * CIN);
      __builtin_amdgcn_sched_barrier(0);
    }

    // MFMA
    f32x4 acc[NT];
    #pragma unroll
    for (int j = 0; j < NT; j++) acc[j] = (f32x4){0.f, 0.f, 0.f, 0.f};
    #pragma unroll
    for (int kt = 0; kt < KT; kt++) {
      const int s  = kt >> 1, cb = (kt & 1) * 32;
      const int chk = ((cb >> 3) + quad) ^ (lr & 7);
      const s16x8 a0 = *(const s16x8*)(wbase + kt * 512);
      #pragma unroll
      for (int j = 0; j < NT; j++) {
        const s16x8 bj = *(const s16x8*)&F[(s * EPB + j * 16 + lr) * CIN + chk * 8];
        // swapped: D[row=edge][col=channel]
        acc[j] = __builtin_amdgcn_mfma_f32_16x16x32_bf16(bj, a0, acc[j], 0, 0, 0);
      }
    }

    // epilogue: lane holds edges (j*16+quad*4+r), channel = ch
    if (tcur < nbx) {
      float s = 0.f, s2 = 0.f;
      #pragma unroll
      for (int j = 0; j < NT; j++) {
        #pragma unroll
        for (int r = 0; r < 4; r++) {
          const int el = j * 16 + quad * 4 + r;
          const size_t eg = (size_t)tcur * EPB + el;
          if (eg < (size_t)E) {
            const float v = acc[j][r] + bv;
            y1b[((size_t)b * E + eg) * 128 + ch] = f2bfh(v);
            s += v; s2 += v * v;
          }
        }
      }
      s  += __shfl_xor(s, 16);  s  += __shfl_xor(s, 32);
      s2 += __shfl_xor(s2, 16); s2 += __shfl_xor(s2, 32);
      if (lane < 16)
        partials[(size_t)(b * 128 + ch) * nbx + tcur] = make_float2(s, s2);
    }
    __syncthreads();
  }
}

// ---------------------------------------------------------------------------
// conv2: gathers bf16 y1b rows, instance-norm+ReLU on the fly
// (stats1 = (-m*r, r)), symmetric features, fragment-major W MFMA,
// y2b bf16 out + partials. Same 4-tile software pipeline.
// ---------------------------------------------------------------------------
__global__ __launch_bounds__(512, 6) void conv2_mfma(
    const u16* __restrict__ x1b, const int* __restrict__ gidx,
    const u16* __restrict__ Wp, const float* __restrict__ bias,
    const float2* __restrict__ stats1,
    u16* __restrict__ y2b, float2* __restrict__ partials, int E, int nbx)
{
  constexpr int CIN = 128, EPB = 32, SUB = 16, KT = 20, NTL = 4;
  constexpr int NT  = EPB / 16;                // 2
  __shared__ __align__(16) u16 F[5 * EPB * CIN];   // 40960 B, swizzled chunks

  const int b  = blockIdx.z;
  const int t  = threadIdx.x;
  const int e_l = t / SUB;                     // 0..31
  const int sub = t % SUB;                     // 0..15 (16B chunk id)
  const int lane = t & 63, wv = t >> 6;
  const int lr = lane & 15, quad = lane >> 4;
  const int tbeg = blockIdx.x * NTL;

  const u16* base  = x1b + (size_t)b * E * 128 + sub * 8;
  const u16* wbase = Wp + ((size_t)wv * KT * 64 + lane) * 8;
  const int pc = (sub ^ (e_l & 7)) * 8;        // swizzled chunk offset

  // tile-invariant: stats (-m*r, r) for this thread's 8 channels, and bias
  f32x4 st[4];
  {
    const float* sp = (const float*)(stats1 + b * 128 + sub * 8);
    #pragma unroll
    for (int q = 0; q < 4; q++) st[q] = *(const f32x4*)(sp + q * 4);
  }
  const int m0 = wv * 16 + quad * 4;
  const float4 bs = *(const float4*)(bias + m0);

  // prologue: gidx + gathers for tile tbeg
  u16x8 raw[5];
  {
    int er = tbeg * EPB + e_l;
    const int e = er < E ? er : E - 1;
    const int4 g = *(const int4*)(gidx + ((size_t)b * E + e) * 4);
    int rows[5] = {e, g.x, g.y, g.z, g.w};
    #pragma unroll
    for (int j = 0; j < 5; j++)
      raw[j] = *(const u16x8*)(base + (size_t)rows[j] * 128);
  }
  __builtin_amdgcn_sched_barrier(0);

  for (int it = 0; it < NTL; ++it) {
    const int tcur = tbeg + it;
    const bool hasNext = (it + 1 < NTL);

    // prefetch next tile's neighbor indices
    int4 gn; int en = 0;
    if (hasNext) {
      int er = (tcur + 1) * EPB + e_l;
      en = er < E ? er : E - 1;
      gn = *(const int4*)(gidx + ((size_t)b * E + en) * 4);
    }

    // stage F from raw: norm+relu (one FMA) then symmetric features
    {
      u16x8 o0, o1, o2, o3, o4;
      #pragma unroll
      for (int c = 0; c < 8; c++) {
        const float nm = st[c >> 1][(c & 1) * 2];
        const float rr = st[c >> 1][(c & 1) * 2 + 1];
        float x[5];
        #pragma unroll
        for (int j = 0; j < 5; j++) {
          float v = fmaf(bf2f(raw[j][c]), rr, nm);
          x[j] = v < 0.f ? 0.f : v;
        }
        o0[c] = f2bfh(x[0]);
        o1[c] = f2bfh(x[1] + x[3]);
        o2[c] = f2bfh(x[2] + x[4]);
        o3[c] = f2bfh(fabsf(x[1] - x[3]));
        o4[c] = f2bfh(fabsf(x[2] - x[4]));
      }
      *(u16x8*)&F[(0 * EPB + e_l) * CIN + pc] = o0;
      *(u16x8*)&F[(1 * EPB + e_l) * CIN + pc] = o1;
      *(u16x8*)&F[(2 * EPB + e_l) * CIN + pc] = o2;
      *(u16x8*)&F[(3 * EPB + e_l) * CIN + pc] = o3;
      *(u16x8*)&F[(4 * EPB + e_l) * CIN + pc] = o4;
    }
    __syncthreads();

    // issue next tile's gathers: fly under MFMA + epilogue + barrier
    if (hasNext) {
      int rows[5] = {en, gn.x, gn.y, gn.z, gn.w};
      #pragma unroll
      for (int j = 0; j < 5; j++)
        raw[j] = *(const u16x8*)(base + (size_t)rows[j] * 128);
      __builtin_amdgcn_sched_barrier(0);
    }

    // MFMA
    f32x4 acc[NT];
    #pragma unroll
    for (int j = 0; j < NT; j++) acc[j] = (f32x4){0.f, 0.f, 0.f, 0.f};
    #pragma unroll
    for (int kt = 0; kt < KT; kt++) {
      const int s  = kt >> 2, cb = (kt & 3) * 32;
      const int chk = ((cb >> 3) + quad) ^ (lr & 7);
      const s16x8 a0 = *(const s16x8*)(wbase + kt * 512);
      #pragma unroll
      for (int j = 0; j < NT; j++) {
        const s16x8 bj = *(const s16x8*)&F[(s * EPB + j * 16 + lr) * CIN + chk * 8];
        acc[j] = __builtin_amdgcn_mfma_f32_16x16x32_bf16(a0, bj, acc[j], 0, 0, 0);
      }
    }

    // epilogue: D[row=channel(quad*4+r)][col=edge(lr)]
    if (tcur < nbx) {
      const size_t ybase = (size_t)b * 128;
      #pragma unroll
      for (int r = 0; r < 4; r++) {
        const int m = m0 + r;
        const float bvv = ((const float*)&bs)[r];
        float s = 0.f, s2 = 0.f;
        #pragma unroll
        for (int j = 0; j < NT; j++) {
          const size_t eg = (size_t)tcur * EPB + j * 16 + lr;
          if (eg < (size_t)E) {
            const float v = acc[j][r] + bvv;
            y2b[(ybase + m) * E + eg] = f2bfh(v);
            s += v; s2 += v * v;
          }
        }
        #pragma unroll
        for (int mk = 1; mk < 16; mk <<= 1) {
          s  += __shfl_xor(s,  mk);
          s2 += __shfl_xor(s2, mk);
        }
        if (lr == 0)
          partials[(size_t)(b * 128 + m) * nbx + tcur] = make_float2(s, s2);
      }
    }
    __syncthreads();
  }
}

// ---------------------------------------------------------------------------
// Reduce per-block partials -> ( -mean*rstd, rstd ) per (b, o) row
// ---------------------------------------------------------------------------
__global__ __launch_bounds__(256) void stats_finalize(
    const float2* __restrict__ partials, float2* __restrict__ stats,
    int nbx, int E)
{
  const int row = blockIdx.x;
  const float2* p = partials + (size_t)row * nbx;
  float s = 0.f, s2 = 0.f;
  for (int i = threadIdx.x; i < nbx; i += 256) {
    const float2 v = p[i];
    s += v.x; s2 += v.y;
  }
  #pragma unroll
  for (int off = 32; off > 0; off >>= 1) {
    s  += __shfl_down(s, off);
    s2 += __shfl_down(s2, off);
  }
  __shared__ float rs[4], rs2[4];
  const int wv = threadIdx.x >> 6;
  if ((threadIdx.x & 63) == 0) { rs[wv] = s; rs2[wv] = s2; }
  __syncthreads();
  if (threadIdx.x == 0) {
    s  = rs[0] + rs[1] + rs[2] + rs[3];
    s2 = rs2[0] + rs2[1] + rs2[2] + rs2[3];
    const float mean = s / E;
    const float var  = s2 / E - mean * mean;
    const float rstd = rsqrtf(var + 1e-5f);
    stats[row] = make_float2(-mean * rstd, rstd);
  }
}

// ---------------------------------------------------------------------------
// Final: out[b,o,e] = relu( fma(y2b, r2, nmr2) + relu(fma(y1b[e,o], r1, nmr1)) )
// Tile 32 o x 64 e; y1b (bf16) read via LDS transpose; out nontemporal.
// ---------------------------------------------------------------------------
__global__ __launch_bounds__(256) void final_k(
    const u16* __restrict__ y2b, const u16* __restrict__ y1b,
    const float2* __restrict__ st1, const float2* __restrict__ st2,
    float* __restrict__ out, int E)
{
  __shared__ float tile[32][65];
  const int b  = blockIdx.z;
  const int o0 = blockIdx.y * 32;
  const int e0 = blockIdx.x * 64;
  const int t  = threadIdx.x;

  // phase 1: load y1b [64e][32ch slice], normalize+relu, write transposed
  {
    const int e_l  = t >> 2;        // 0..63
    const int part = t & 3;         // 0..3  -> 8 channels each
    const int eg   = e0 + e_l;
    if (eg < E) {
      const u16* src = y1b + ((size_t)b * E + eg) * 128 + o0 + part * 8;
      const u16x8 v = *(const u16x8*)src;
      #pragma unroll
      for (int i = 0; i < 8; i++) {
        const float2 s1 = st1[b * 128 + o0 + part * 8 + i];
        float x = fmaf(bf2f(v[i]), s1.y, s1.x);
        tile[part * 8 + i][e_l] = x < 0.f ? 0.f : x;
      }
    }
  }
  __syncthreads();

  // phase 2: y2 + residual, relu, store
  {
    const int col = t & 63;
    const int r   = t >> 6;
    const int eg  = e0 + col;
    if (eg < E) {
      #pragma unroll
      for (int k = 0; k < 8; k++) {
        const int o = o0 + r * 8 + k;
        const float2 s2 = st2[b * 128 + o];
        const size_t idx = ((size_t)b * 128 + o) * E + eg;
        float v = fmaf(bf2f(y2b[idx]), s2.y, s2.x) + tile[r * 8 + k][col];
        v = v < 0.f ? 0.f : v;
        __builtin_nontemporal_store(v, out + idx);
      }
    }
  }
}

// ---------------------------------------------------------------------------
extern "C" void kernel_launch(void* const* d_in, const int* in_sizes, int n_in,
                              void* d_out, int out_size, void* d_ws, size_t ws_size,
                              hipStream_t stream)
{
  const float* fe  = (const float*)d_in[0];
  const int*   gmm = (const int*)d_in[1];
  const float* w1  = (const float*)d_in[2];
  const float* b1  = (const float*)d_in[3];
  const float* w2  = (const float*)d_in[4];
  const float* b2  = (const float*)d_in[5];
  float* out = (float*)d_out;

  const int B = 2, CIN = 64, COUT = 128;
  const int E = in_sizes[0] / (B * CIN);   // 100000
  const int nbx1 = (E + 63) / 64;          // conv1 tiles: EPB=64
  const int nbx2 = (E + 31) / 32;          // conv2 tiles: EPB=32
  const int gb1  = (nbx1 + 3) / 4;         // 4 tiles per block (pipeline)
  const int gb2  = (nbx2 + 3) / 4;

  // workspace: regA = feT (bf16, dead after conv1) aliased with y2b (bf16)
  char* p = (char*)d_ws;
  auto alloc = [&](size_t bytes) -> char* {
    char* q = p; p += (bytes + 255) & ~(size_t)255; return q;
  };
  const size_t feT_b = (size_t)B * E * CIN * 2;        // 25.6 MB
  const size_t y2_b  = (size_t)B * COUT * E * 2;       // 51.2 MB
  char* regA = alloc(y2_b > feT_b ? y2_b : feT_b);
  u16*   feT = (u16*)regA;
  u16*   y2b = (u16*)regA;
  u16*   y1b = (u16*)alloc((size_t)B * E * COUT * 2);  // 51.2 MB, persists
  float2* stats1 = (float2*)alloc((size_t)B * COUT * sizeof(float2));
  float2* stats2 = (float2*)alloc((size_t)B * COUT * sizeof(float2));
  u16* w1b = (u16*)alloc((size_t)COUT * CIN * 5 * 2);
  u16* w2b = (u16*)alloc((size_t)COUT * COUT * 5 * 2);
  // partials scratch in d_out: dead before final_k writes out
  float2* partials = (float2*)d_out;   // <= 256*nbx2*8B = 6.4 MB << out_size

  const int n_w1 = COUT * CIN * 5, n_w2 = COUT * COUT * 5;
  prep_w <<<dim3((n_w1 + 255) / 256), 256, 0, stream>>>(w1, w1b, COUT, CIN);
  prep_w <<<dim3((n_w2 + 255) / 256), 256, 0, stream>>>(w2, w2b, COUT, COUT);

  transpose64 <<<dim3((E + 63) / 64, 1, B), 256, 0, stream>>>(fe, feT, E);
  conv1_mfma <<<dim3(gb1, 1, B), 512, 0, stream>>>(feT, gmm, w1b, b1, y1b, partials, E, nbx1);
  stats_finalize <<<dim3(B * COUT), 256, 0, stream>>>(partials, stats1, nbx1, E);
  conv2_mfma <<<dim3(gb2, 1, B), 512, 0, stream>>>(y1b, gmm, w2b, b2, stats1, y2b, partials, E, nbx2);
  stats_finalize <<<dim3(B * COUT), 256, 0, stream>>>(partials, stats2, nbx2, E);
  final_k <<<dim3((E + 63) / 64, COUT / 32, B), 256, 0, stream>>>(y2b, y1b, stats1, stats2, out, E);
}

// Round 10
// 325.996 us; speedup vs baseline: 1.3747x; 1.3747x over previous
//
#include <hip/hip_runtime.h>
#include <hip/hip_bf16.h>

typedef unsigned short u16;
typedef __attribute__((ext_vector_type(4))) unsigned short u16x4;
typedef __attribute__((ext_vector_type(8))) unsigned short u16x8;
typedef __attribute__((ext_vector_type(8))) short s16x8;
typedef __attribute__((ext_vector_type(4))) float f32x4;

__device__ __forceinline__ float bf2f(u16 u){
  union { unsigned int i; float f; } v; v.i = ((unsigned int)u) << 16; return v.f;
}
__device__ __forceinline__ u16 f2bf(float f){
  union { float f; unsigned int i; } v; v.f = f;
  unsigned int r = v.i + 0x7fffu + ((v.i >> 16) & 1u);   // round-nearest-even
  return (u16)(r >> 16);
}
// compiler-lowered RNE convert (gfx950: v_cvt_pk_bf16_f32; m240: use the
// intrinsic, never hand-written asm)
__device__ __forceinline__ u16 f2bfh(float f){
  __hip_bfloat16 h = __float2bfloat16(f);
  return *reinterpret_cast<u16*>(&h);
}

// ---------------------------------------------------------------------------
// Weight prep: fp32 [COUT][CIN][5] -> fragment-major bf16
//   Wp[wv][kt][lane][8],  wv=o/16, lane=quad*16+lr,
//   element (wv,kt,lane,i) = W[o=wv*16+(lane&15)][k=kt*32+(lane>>4)*8+i],
//   k = s*CIN + c.  A wave's fragment load = 1 KB contiguous.
// ---------------------------------------------------------------------------
__global__ __launch_bounds__(256) void prep_w(
    const float* __restrict__ src, u16* __restrict__ dst, int cout, int cin)
{
  const int n  = cout * cin * 5;
  const int KT = (cin * 5) / 32;
  const int i = blockIdx.x * 256 + threadIdx.x;
  if (i >= n) return;
  const int ii   = i & 7;
  const int lane = (i >> 3) & 63;
  const int kt   = (i >> 9) % KT;
  const int wv   = i / (KT * 512);
  const int o = wv * 16 + (lane & 15);
  const int k = kt * 32 + (lane >> 4) * 8 + ii;
  const int s = k / cin;
  const int c = k - s * cin;
  dst[i] = f2bf(src[(o * cin + c) * 5 + s]);
}

// ---------------------------------------------------------------------------
// K0: transpose fe [B,64,E] (fp32) -> feT [B,E,64] (bf16)
// ---------------------------------------------------------------------------
__global__ __launch_bounds__(256) void transpose64(
    const float* __restrict__ x, u16* __restrict__ xT, int E)
{
  __shared__ u16 tile[64][66];
  const int b   = blockIdx.z;
  const int e0  = blockIdx.x * 64;
  const int col = threadIdx.x & 63;
  const int r   = threadIdx.x >> 6;
  const int e   = e0 + col;
  #pragma unroll
  for (int k = 0; k < 16; k++) {
    const int c = r * 16 + k;
    float v = 0.f;
    if (e < E) v = x[((size_t)b * 64 + c) * (size_t)E + e];
    tile[c][col] = f2bf(v);
  }
  __syncthreads();
  const int e_l  = threadIdx.x >> 2;
  const int part = threadIdx.x & 3;
  const int eg   = e0 + e_l;
  if (eg < E) {
    u16* dst = xT + ((size_t)b * E + eg) * 64 + part * 16;
    #pragma unroll
    for (int h = 0; h < 2; h++) {
      u16x8 v;
      #pragma unroll
      for (int cc = 0; cc < 8; cc++) v[cc] = tile[part * 16 + h * 8 + cc][e_l];
      *(u16x8*)(dst + h * 8) = v;
    }
  }
}

// ---------------------------------------------------------------------------
// conv1: y1b[b,e,o] = bf16( sum_k W[o,k]*F[k,e] + bias[o] )  (pre-norm,
// EDGE-major bf16). Swapped MFMA: D[row=edge][col=channel].
// Fragment-major W (coalesced dwordx4/lane/fragment).
// LDS F un-padded + XOR chunk swizzle, 40960 B.
// ---------------------------------------------------------------------------
__global__ __launch_bounds__(512, 6) void conv1_mfma(
    const u16* __restrict__ xT, const int* __restrict__ gidx,
    const u16* __restrict__ Wp, const float* __restrict__ bias,
    u16* __restrict__ y1b, float2* __restrict__ partials, int E, int nbx)
{
  constexpr int CIN = 64, EPB = 64, SUB = 8, KT = 10;
  constexpr int NT  = EPB / 16;                // 4
  __shared__ __align__(16) u16 F[5 * EPB * CIN];   // 40960 B, swizzled chunks

  const int b  = blockIdx.z;
  const int bx = blockIdx.x;
  const int t  = threadIdx.x;
  const int e_l = t / SUB;                     // 0..63
  const int sub = t % SUB;                     // 0..7 (16B chunk id)
  const int lane = t & 63, wv = t >> 6;
  const int lr = lane & 15, quad = lane >> 4;
  const size_t e_raw = (size_t)bx * EPB + e_l;
  const int e = (int)(e_raw < (size_t)E ? e_raw : (size_t)(E - 1));

  int rows[5];
  {
    const int4 g = *(const int4*)(gidx + ((size_t)b * E + e) * 4);
    rows[0] = e; rows[1] = g.x; rows[2] = g.y; rows[3] = g.z; rows[4] = g.w;
  }
  const u16* base = xT + (size_t)b * E * CIN + sub * 8;
  const u16* wbase = Wp + ((size_t)wv * KT * 64 + lane) * 8;

  // force-issue all 5 gather loads before any use
  u16x8 raw[5];
  #pragma unroll
  for (int j = 0; j < 5; j++)
    raw[j] = *(const u16x8*)(base + (size_t)rows[j] * CIN);
  __builtin_amdgcn_sched_barrier(0);

  {
    const int pc = (sub ^ (e_l & 7)) * 8;      // swizzled chunk offset
    u16x8 o1, o2, o3, o4;
    #pragma unroll
    for (int c = 0; c < 8; c++) {
      const float a1 = bf2f(raw[1][c]), a2 = bf2f(raw[2][c]);
      const float a3 = bf2f(raw[3][c]), a4 = bf2f(raw[4][c]);
      o1[c] = f2bfh(a1 + a3);
      o2[c] = f2bfh(a2 + a4);
      o3[c] = f2bfh(fabsf(a1 - a3));
      o4[c] = f2bfh(fabsf(a2 - a4));
    }
    *(u16x8*)&F[(0 * EPB + e_l) * CIN + pc] = raw[0];
    *(u16x8*)&F[(1 * EPB + e_l) * CIN + pc] = o1;
    *(u16x8*)&F[(2 * EPB + e_l) * CIN + pc] = o2;
    *(u16x8*)&F[(3 * EPB + e_l) * CIN + pc] = o3;
    *(u16x8*)&F[(4 * EPB + e_l) * CIN + pc] = o4;
  }
  __syncthreads();

  f32x4 acc[NT];
  #pragma unroll
  for (int j = 0; j < NT; j++) acc[j] = (f32x4){0.f, 0.f, 0.f, 0.f};
  #pragma unroll
  for (int kt = 0; kt < KT; kt++) {
    const int s  = kt >> 1, cb = (kt & 1) * 32;
    const int chk = ((cb >> 3) + quad) ^ (lr & 7);
    const s16x8 a0 = *(const s16x8*)(wbase + kt * 512);
    #pragma unroll
    for (int j = 0; j < NT; j++) {
      const s16x8 bj = *(const s16x8*)&F[(s * EPB + j * 16 + lr) * CIN + chk * 8];
      // swapped: D[row=edge][col=channel]
      acc[j] = __builtin_amdgcn_mfma_f32_16x16x32_bf16(bj, a0, acc[j], 0, 0, 0);
    }
  }

  // epilogue: lane holds edges (j*16+quad*4+r), channel = wv*16+lr
  const int ch = wv * 16 + lr;
  const float bv = bias[ch];
  float s = 0.f, s2 = 0.f;
  #pragma unroll
  for (int j = 0; j < NT; j++) {
    #pragma unroll
    for (int r = 0; r < 4; r++) {
      const int el = j * 16 + quad * 4 + r;
      const size_t eg = (size_t)bx * EPB + el;
      if (eg < (size_t)E) {
        const float v = acc[j][r] + bv;
        y1b[((size_t)b * E + eg) * 128 + ch] = f2bfh(v);
        s += v; s2 += v * v;
      }
    }
  }
  s  += __shfl_xor(s, 16);  s  += __shfl_xor(s, 32);
  s2 += __shfl_xor(s2, 16); s2 += __shfl_xor(s2, 32);
  if (lane < 16)
    partials[(size_t)(b * 128 + ch) * nbx + bx] = make_float2(s, s2);
}

// ---------------------------------------------------------------------------
// conv2: gathers bf16 y1b rows, applies instance-norm+ReLU on the fly
// (stats1 = (-m*r, r), one FMA per value), builds symmetric features,
// MFMA with fragment-major W. y2 output in bf16 (stats from fp32 acc).
// ---------------------------------------------------------------------------
__global__ __launch_bounds__(512, 6) void conv2_mfma(
    const u16* __restrict__ x1b, const int* __restrict__ gidx,
    const u16* __restrict__ Wp, const float* __restrict__ bias,
    const float2* __restrict__ stats1,
    u16* __restrict__ y2b, float2* __restrict__ partials, int E, int nbx)
{
  constexpr int CIN = 128, EPB = 32, SUB = 16, KT = 20;
  constexpr int NT  = EPB / 16;                // 2
  __shared__ __align__(16) u16 F[5 * EPB * CIN];   // 40960 B, swizzled chunks

  const int b  = blockIdx.z;
  const int bx = blockIdx.x;
  const int t  = threadIdx.x;
  const int e_l = t / SUB;                     // 0..31
  const int sub = t % SUB;                     // 0..15 (16B chunk id)
  const int lane = t & 63, wv = t >> 6;
  const int lr = lane & 15, quad = lane >> 4;
  const size_t e_raw = (size_t)bx * EPB + e_l;
  const int e = (int)(e_raw < (size_t)E ? e_raw : (size_t)(E - 1));

  int rows[5];
  {
    const int4 g = *(const int4*)(gidx + ((size_t)b * E + e) * 4);
    rows[0] = e; rows[1] = g.x; rows[2] = g.y; rows[3] = g.z; rows[4] = g.w;
  }
  const u16* base = x1b + (size_t)b * E * 128 + sub * 8;
  const u16* wbase = Wp + ((size_t)wv * KT * 64 + lane) * 8;

  // force-issue all 5 gather loads + stats loads before any use
  u16x8 raw[5];
  #pragma unroll
  for (int j = 0; j < 5; j++)
    raw[j] = *(const u16x8*)(base + (size_t)rows[j] * 128);
  f32x4 st[4];   // {nmr,r} x 8 channels (this thread's chunk), L2-hot
  {
    const float* sp = (const float*)(stats1 + b * 128 + sub * 8);
    #pragma unroll
    for (int q = 0; q < 4; q++) st[q] = *(const f32x4*)(sp + q * 4);
  }
  __builtin_amdgcn_sched_barrier(0);

  {
    const int pc = (sub ^ (e_l & 7)) * 8;      // swizzled chunk offset
    u16x8 o0, o1, o2, o3, o4;
    #pragma unroll
    for (int c = 0; c < 8; c++) {
      const float nm = st[c >> 1][(c & 1) * 2];
      const float rr = st[c >> 1][(c & 1) * 2 + 1];
      float x[5];
      #pragma unroll
      for (int j = 0; j < 5; j++) {
        float v = fmaf(bf2f(raw[j][c]), rr, nm);
        x[j] = v < 0.f ? 0.f : v;
      }
      o0[c] = f2bfh(x[0]);
      o1[c] = f2bfh(x[1] + x[3]);
      o2[c] = f2bfh(x[2] + x[4]);
      o3[c] = f2bfh(fabsf(x[1] - x[3]));
      o4[c] = f2bfh(fabsf(x[2] - x[4]));
    }
    *(u16x8*)&F[(0 * EPB + e_l) * CIN + pc] = o0;
    *(u16x8*)&F[(1 * EPB + e_l) * CIN + pc] = o1;
    *(u16x8*)&F[(2 * EPB + e_l) * CIN + pc] = o2;
    *(u16x8*)&F[(3 * EPB + e_l) * CIN + pc] = o3;
    *(u16x8*)&F[(4 * EPB + e_l) * CIN + pc] = o4;
  }
  __syncthreads();

  f32x4 acc[NT];
  #pragma unroll
  for (int j = 0; j < NT; j++) acc[j] = (f32x4){0.f, 0.f, 0.f, 0.f};
  #pragma unroll
  for (int kt = 0; kt < KT; kt++) {
    const int s  = kt >> 2, cb = (kt & 3) * 32;
    const int chk = ((cb >> 3) + quad) ^ (lr & 7);
    const s16x8 a0 = *(const s16x8*)(wbase + kt * 512);
    #pragma unroll
    for (int j = 0; j < NT; j++) {
      const s16x8 bj = *(const s16x8*)&F[(s * EPB + j * 16 + lr) * CIN + chk * 8];
      acc[j] = __builtin_amdgcn_mfma_f32_16x16x32_bf16(a0, bj, acc[j], 0, 0, 0);
    }
  }

  // epilogue: D[row=channel(quad*4+r)][col=edge(lr)]
  const size_t ybase = (size_t)b * 128;
  const int m0 = wv * 16 + quad * 4;
  const float4 bs = *(const float4*)(bias + m0);
  #pragma unroll
  for (int r = 0; r < 4; r++) {
    const int m = m0 + r;
    const float bv = ((const float*)&bs)[r];
    float s = 0.f, s2 = 0.f;
    #pragma unroll
    for (int j = 0; j < NT; j++) {
      const size_t eg = (size_t)bx * EPB + j * 16 + lr;
      if (eg < (size_t)E) {
        const float v = acc[j][r] + bv;
        y2b[(ybase + m) * E + eg] = f2bfh(v);
        s += v; s2 += v * v;
      }
    }
    #pragma unroll
    for (int mk = 1; mk < 16; mk <<= 1) {
      s  += __shfl_xor(s,  mk);
      s2 += __shfl_xor(s2, mk);
    }
    if (lr == 0)
      partials[(size_t)(b * 128 + m) * nbx + bx] = make_float2(s, s2);
  }
}

// ---------------------------------------------------------------------------
// Reduce per-block partials -> ( -mean*rstd, rstd ) per (b, o) row
// ---------------------------------------------------------------------------
__global__ __launch_bounds__(256) void stats_finalize(
    const float2* __restrict__ partials, float2* __restrict__ stats,
    int nbx, int E)
{
  const int row = blockIdx.x;
  const float2* p = partials + (size_t)row * nbx;
  float s = 0.f, s2 = 0.f;
  for (int i = threadIdx.x; i < nbx; i += 256) {
    const float2 v = p[i];
    s += v.x; s2 += v.y;
  }
  #pragma unroll
  for (int off = 32; off > 0; off >>= 1) {
    s  += __shfl_down(s, off);
    s2 += __shfl_down(s2, off);
  }
  __shared__ float rs[4], rs2[4];
  const int wv = threadIdx.x >> 6;
  if ((threadIdx.x & 63) == 0) { rs[wv] = s; rs2[wv] = s2; }
  __syncthreads();
  if (threadIdx.x == 0) {
    s  = rs[0] + rs[1] + rs[2] + rs[3];
    s2 = rs2[0] + rs2[1] + rs2[2] + rs2[3];
    const float mean = s / E;
    const float var  = s2 / E - mean * mean;
    const float rstd = rsqrtf(var + 1e-5f);
    stats[row] = make_float2(-mean * rstd, rstd);
  }
}

// ---------------------------------------------------------------------------
// Final: out[b,o,e] = relu( fma(y2b, r2, nmr2) + relu(fma(y1b[e,o], r1, nmr1)) )
// Tile 32 o x 64 e; y1b (bf16) read via LDS transpose; out nontemporal.
// ---------------------------------------------------------------------------
__global__ __launch_bounds__(256) void final_k(
    const u16* __restrict__ y2b, const u16* __restrict__ y1b,
    const float2* __restrict__ st1, const float2* __restrict__ st2,
    float* __restrict__ out, int E)
{
  __shared__ float tile[32][65];
  const int b  = blockIdx.z;
  const int o0 = blockIdx.y * 32;
  const int e0 = blockIdx.x * 64;
  const int t  = threadIdx.x;

  // phase 1: load y1b [64e][32ch slice], normalize+relu, write transposed
  {
    const int e_l  = t >> 2;        // 0..63
    const int part = t & 3;         // 0..3  -> 8 channels each
    const int eg   = e0 + e_l;
    if (eg < E) {
      const u16* src = y1b + ((size_t)b * E + eg) * 128 + o0 + part * 8;
      const u16x8 v = *(const u16x8*)src;
      #pragma unroll
      for (int i = 0; i < 8; i++) {
        const float2 s1 = st1[b * 128 + o0 + part * 8 + i];
        float x = fmaf(bf2f(v[i]), s1.y, s1.x);
        tile[part * 8 + i][e_l] = x < 0.f ? 0.f : x;
      }
    }
  }
  __syncthreads();

  // phase 2: y2 + residual, relu, store
  {
    const int col = t & 63;
    const int r   = t >> 6;
    const int eg  = e0 + col;
    if (eg < E) {
      #pragma unroll
      for (int k = 0; k < 8; k++) {
        const int o = o0 + r * 8 + k;
        const float2 s2 = st2[b * 128 + o];
        const size_t idx = ((size_t)b * 128 + o) * E + eg;
        float v = fmaf(bf2f(y2b[idx]), s2.y, s2.x) + tile[r * 8 + k][col];
        v = v < 0.f ? 0.f : v;
        __builtin_nontemporal_store(v, out + idx);
      }
    }
  }
}

// ---------------------------------------------------------------------------
extern "C" void kernel_launch(void* const* d_in, const int* in_sizes, int n_in,
                              void* d_out, int out_size, void* d_ws, size_t ws_size,
                              hipStream_t stream)
{
  const float* fe  = (const float*)d_in[0];
  const int*   gmm = (const int*)d_in[1];
  const float* w1  = (const float*)d_in[2];
  const float* b1  = (const float*)d_in[3];
  const float* w2  = (const float*)d_in[4];
  const float* b2  = (const float*)d_in[5];
  float* out = (float*)d_out;

  const int B = 2, CIN = 64, COUT = 128;
  const int E = in_sizes[0] / (B * CIN);   // 100000
  const int nbx1 = (E + 63) / 64;          // conv1: EPB=64
  const int nbx2 = (E + 31) / 32;          // conv2: EPB=32

  // workspace: regA = feT (bf16, dead after conv1) aliased with y2b (bf16)
  char* p = (char*)d_ws;
  auto alloc = [&](size_t bytes) -> char* {
    char* q = p; p += (bytes + 255) & ~(size_t)255; return q;
  };
  const size_t feT_b = (size_t)B * E * CIN * 2;        // 25.6 MB
  const size_t y2_b  = (size_t)B * COUT * E * 2;       // 51.2 MB
  char* regA = alloc(y2_b > feT_b ? y2_b : feT_b);
  u16*   feT = (u16*)regA;
  u16*   y2b = (u16*)regA;
  u16*   y1b = (u16*)alloc((size_t)B * E * COUT * 2);  // 51.2 MB, persists
  float2* stats1 = (float2*)alloc((size_t)B * COUT * sizeof(float2));
  float2* stats2 = (float2*)alloc((size_t)B * COUT * sizeof(float2));
  u16* w1b = (u16*)alloc((size_t)COUT * CIN * 5 * 2);
  u16* w2b = (u16*)alloc((size_t)COUT * COUT * 5 * 2);
  // partials scratch in d_out: dead before final_k writes out
  float2* partials = (float2*)d_out;   // <= 256*nbx2*8B = 6.4 MB << out_size

  const int n_w1 = COUT * CIN * 5, n_w2 = COUT * COUT * 5;
  prep_w <<<dim3((n_w1 + 255) / 256), 256, 0, stream>>>(w1, w1b, COUT, CIN);
  prep_w <<<dim3((n_w2 + 255) / 256), 256, 0, stream>>>(w2, w2b, COUT, COUT);

  transpose64 <<<dim3((E + 63) / 64, 1, B), 256, 0, stream>>>(fe, feT, E);
  conv1_mfma <<<dim3(nbx1, 1, B), 512, 0, stream>>>(feT, gmm, w1b, b1, y1b, partials, E, nbx1);
  stats_finalize <<<dim3(B * COUT), 256, 0, stream>>>(partials, stats1, nbx1, E);
  conv2_mfma <<<dim3(nbx2, 1, B), 512, 0, stream>>>(y1b, gmm, w2b, b2, stats1, y2b, partials, E, nbx2);
  stats_finalize <<<dim3(B * COUT), 256, 0, stream>>>(partials, stats2, nbx2, E);
  final_k <<<dim3((E + 63) / 64, COUT / 32, B), 256, 0, stream>>>(y2b, y1b, stats1, stats2, out, E);
}